// Round 3
// baseline (836.284 us; speedup 1.0000x reference)
//
#include <hip/hip_runtime.h>
#include <stdint.h>

// TPTransMatrix: out = x (16384 x 4096) times block_diag(blocks[0..7]) where
// blocks[kb] is 512x512. Grouped bf16-MFMA GEMM: M=16384, K=512, N=512, x8 groups.
//
// R3: ZERO main-loop barriers. R0-R2 all pinned at ~245 us despite traffic
// going from 953->576 MB (ideal) -> latency/serialization-bound on the
// per-K-step __syncthreads + vmcnt(0) drain (m233: that drain is ~72% of a
// 2-phase loop's critical path). New structure:
//   - whole B panel (BN=64 x K=512 bf16 = 64 KB, XOR-swizzled) staged to LDS
//     ONCE per WG via global_load_lds; single barrier; then barrier-free K-loop.
//   - A goes global->reg directly (per-lane 32 B = exact MFMA fragment),
//     packed fp32->bf16 in-register. No A LDS, no ds_write, no sync.
//   - manual depth-1 A prefetch (ab[2][8], full unroll -> static indices).
//   - BM=256, 512 threads (8 waves), 2 WG/CU (16 waves/CU) for latency hiding.

#define HID 4096
#define KD  512
#define NKB 8
#define BM  256
#define BN  64
#define BK  32
#define NKK (KD / BK)         // 16 K-steps
#define MTILES 64             // 16384 / BM
#define NNT    8              // 512 / BN
#define NWG   (MTILES * NKB * NNT)   // 4096

typedef __attribute__((ext_vector_type(4))) float    f32x4;
typedef __attribute__((ext_vector_type(8))) short    s16x8;
typedef __attribute__((ext_vector_type(4))) uint32_t u32x4;

// bf16 transposed copy of blocks: g_bt[kb][c][b] = bf16(blocks[kb][b][c]).
__device__ uint16_t g_bt[(size_t)NKB * KD * KD];

__device__ __forceinline__ void async_copy16(const void* g, void* l) {
  __builtin_amdgcn_global_load_lds((const __attribute__((address_space(1))) void*)g,
                                   (__attribute__((address_space(3))) void*)l,
                                   16, 0, 0);
}

// fp32 -> bf16 RNE
__device__ __forceinline__ uint16_t f2bf_rne(float f) {
  uint32_t u = __float_as_uint(f);
  u += 0x7fffu + ((u >> 16) & 1u);
  return (uint16_t)(u >> 16);
}

// ---------------- prep: transpose + convert blocks -> g_bt ----------------
__global__ void convert_blocks_k(const float* __restrict__ blocks) {
  __shared__ float tile[32][33];                 // +1 pad: conflict-free transpose
  const int kb = blockIdx.z;
  const int c0 = blockIdx.x * 32;
  const int b0 = blockIdx.y * 32;
  const int tx = threadIdx.x;                    // 0..31
  const int ty = threadIdx.y;                    // 0..7
  const float* src = blocks + ((size_t)kb * KD + b0) * KD + c0;
#pragma unroll
  for (int i = 0; i < 4; ++i) {
    const int r = ty + i * 8;
    tile[r][tx] = src[(size_t)r * KD + tx];      // coalesced in c
  }
  __syncthreads();
  uint16_t* dst = g_bt + ((size_t)kb * KD + c0) * KD + b0;
#pragma unroll
  for (int i = 0; i < 4; ++i) {
    const int r = ty + i * 8;
    dst[(size_t)r * KD + tx] = f2bf_rne(tile[tx][r]);   // coalesced in b
  }
}

// ---------------- main grouped GEMM ----------------
__global__ __launch_bounds__(512, 2)
void grouped_gemm_k(const float* __restrict__ x, float* __restrict__ out) {
  __shared__ uint16_t lB[BN * KD];   // 64 KB: whole B panel, XOR-swizzled rows

  const int tid = threadIdx.x;

  // XCD-aware remap: the 8 nt-sharers of an A slice (logical-consecutive)
  // land stride-8 in pid -> same XCD -> A refetches are that XCD's L2 hits.
  const int pid = blockIdx.x;
  const int wg  = (pid & 7) * (NWG / 8) + (pid >> 3);
  const int nt  =  wg       & 7;
  const int kb  = (wg >> 3) & 7;
  const int mt  =  wg >> 6;

  const int wave = tid >> 6;
  const int lane = tid & 63;
  const int ln   = lane & 15;
  const int qd   = lane >> 4;
  const int wm   = (wave & 3) * 64;   // 4 m-waves
  const int wn   = (wave >> 2) * 32;  // 2 n-waves

  // ---- B panel staging: linear LDS dst, inverse-swizzled global src (m173) ----
  // LDS layout: row n (0..63) at n*1024 bytes; 16B chunk at koff holds
  // g_bt[kb][nt*64+n][ (koff ^ ((n&7)<<4)) /2 .. +7 ].
  const uint8_t* gb = (const uint8_t*)g_bt + ((size_t)(kb * KD + nt * BN)) * KD * 2;
#pragma unroll
  for (int i = 0; i < 8; ++i) {
    const int L    = (tid + 512 * i) * 16;       // linear LDS byte offset
    const int n    = L >> 10;
    const int koff = L & 1023;
    async_copy16(gb + (size_t)n * 1024 + (koff ^ ((n & 7) << 4)),
                 (uint8_t*)lB + L);
  }

  // ---- A: direct global->reg. Lane (ln,qd), frag mi reads 32 B contiguous:
  // x[mt*BM + wm + mi*16 + ln][kb*512 + k0 + qd*8 .. +7]  (fp32)
  const float* aptr = x + (size_t)(mt * BM + wm + ln) * HID + kb * KD + qd * 8;

  f32x4 acc[4][2];
#pragma unroll
  for (int mi = 0; mi < 4; ++mi)
#pragma unroll
    for (int ni = 0; ni < 2; ++ni)
      acc[mi][ni] = (f32x4){0.f, 0.f, 0.f, 0.f};

  // prologue: load K-step 0 A fragments
  f32x4 ab[2][8];
#pragma unroll
  for (int mi = 0; mi < 4; ++mi) {
    const float* p = aptr + (size_t)mi * 16 * HID;
    ab[0][mi * 2]     = *(const f32x4*)(p);
    ab[0][mi * 2 + 1] = *(const f32x4*)(p + 4);
  }

  __syncthreads();   // B panel resident; the ONLY barrier

  const int rowbase = wn + ln;
#pragma unroll
  for (int kk = 0; kk < NKK; ++kk) {
    const int cb = kk & 1, nb = cb ^ 1;
    const int k1 = ((kk + 1) & (NKK - 1)) * BK;  // kk=15: dead reload of step 0
    // issue next step's A loads first: a full iteration of slack before use
#pragma unroll
    for (int mi = 0; mi < 4; ++mi) {
      const float* p = aptr + (size_t)mi * 16 * HID + k1;
      ab[nb][mi * 2]     = *(const f32x4*)(p);
      ab[nb][mi * 2 + 1] = *(const f32x4*)(p + 4);
    }

    // pack current step's A to bf16 (truncate): 1 v_perm per 2 elems
    s16x8 af[4];
#pragma unroll
    for (int mi = 0; mi < 4; ++mi) {
      const f32x4 lo = ab[cb][mi * 2];
      const f32x4 hi = ab[cb][mi * 2 + 1];
      u32x4 w;
      w.x = __builtin_amdgcn_perm(__float_as_uint(lo.y), __float_as_uint(lo.x), 0x07060302u);
      w.y = __builtin_amdgcn_perm(__float_as_uint(lo.w), __float_as_uint(lo.z), 0x07060302u);
      w.z = __builtin_amdgcn_perm(__float_as_uint(hi.y), __float_as_uint(hi.x), 0x07060302u);
      w.w = __builtin_amdgcn_perm(__float_as_uint(hi.w), __float_as_uint(hi.z), 0x07060302u);
      af[mi] = __builtin_bit_cast(s16x8, w);
    }

    // B fragments from resident panel (swizzled; 2-way bank alias = free)
    s16x8 bf[2];
#pragma unroll
    for (int ni = 0; ni < 2; ++ni) {
      const int row = rowbase + ni * 16;
      const int off = (kk * 64 + qd * 16) ^ ((row & 7) << 4);
      bf[ni] = *(const s16x8*)((const uint8_t*)lB + (size_t)row * 1024 + off);
    }

    // Swapped operands: D = Bt x At => lane(ln,qd) reg r holds
    // out[m = mbase+mi*16+ln][n = nbase+ni*16+qd*4+r]
#pragma unroll
    for (int mi = 0; mi < 4; ++mi)
#pragma unroll
      for (int ni = 0; ni < 2; ++ni)
        acc[mi][ni] = __builtin_amdgcn_mfma_f32_16x16x32_bf16(bf[ni], af[mi], acc[mi][ni], 0, 0, 0);
  }

  // epilogue: 4 consecutive n per reg -> aligned dwordx4 nontemporal stores
  const int mbase = mt * BM + wm;
  const int nbase = kb * KD + nt * BN + wn + qd * 4;
#pragma unroll
  for (int mi = 0; mi < 4; ++mi) {
    float* orow = out + (size_t)(mbase + mi * 16 + ln) * HID + nbase;
#pragma unroll
    for (int ni = 0; ni < 2; ++ni)
      __builtin_nontemporal_store(acc[mi][ni], (f32x4*)(orow + ni * 16));
  }
}

extern "C" void kernel_launch(void* const* d_in, const int* in_sizes, int n_in,
                              void* d_out, int out_size, void* d_ws, size_t ws_size,
                              hipStream_t stream) {
  const float* x      = (const float*)d_in[0];   // [4,4096,4096] fp32 = 16384 x 4096
  const float* blocks = (const float*)d_in[1];   // [8,512,512] fp32
  float* out = (float*)d_out;
  (void)d_ws; (void)ws_size; (void)in_sizes; (void)n_in; (void)out_size;

  convert_blocks_k<<<dim3(16, 16, 8), dim3(32, 8, 1), 0, stream>>>(blocks);
  grouped_gemm_k<<<dim3(NWG, 1, 1), dim3(512, 1, 1), 0, stream>>>(x, out);
}